// Round 2
// baseline (874.468 us; speedup 1.0000x reference)
//
#include <hip/hip_runtime.h>
#include <hip/hip_bf16.h>

typedef __attribute__((ext_vector_type(8))) short bf16x8;
typedef __attribute__((ext_vector_type(4))) float f32x4;

#define BB 8
#define NWIN 64
#define PN 160
#define EN 512
#define HN 8
#define DN 64

static __device__ __forceinline__ unsigned short f2bf(float f) {
  unsigned int u = __builtin_bit_cast(unsigned int, f);
  u += 0x7fffu + ((u >> 16) & 1u);
  return (unsigned short)(u >> 16);
}
static __device__ __forceinline__ unsigned int packbf2(float a, float b) {
  return (unsigned int)f2bf(a) | ((unsigned int)f2bf(b) << 16);
}

// ============ projection: out_z = (X @ W_z^T + b_z) (*0.125 for q) =========
// X: [81920 x 512] f32 row-major. W: [512 x 512] f32 (row f = output feature).
// out layout: [z][B][H][NW][P][D] bf16.
__global__ __launch_bounds__(256)
void proj_kernel(const float* __restrict__ X,
                 const float* __restrict__ Wq, const float* __restrict__ Bq,
                 const float* __restrict__ Wk, const float* __restrict__ Bk,
                 const float* __restrict__ Wv, const float* __restrict__ Bv,
                 unsigned short* __restrict__ qkv) {
  __shared__ unsigned short As[128 * 64];  // 128 rows x 64 k, XOR-swizzled 128B rows
  __shared__ unsigned short Bs[128 * 64];

  const int tid = threadIdx.x;
  const int lane = tid & 63;
  const int lr = lane & 15, lg = lane >> 4;
  const int wave = tid >> 6;
  const int wr = (wave >> 1) * 64;   // wave row quadrant
  const int wc = (wave & 1) * 64;    // wave col quadrant

  const int nz = blockIdx.x;         // 0..11 : (z, n-tile)
  const int z = nz >> 2;
  const int n0 = (nz & 3) * 128;
  const int m0 = blockIdx.y * 128;

  const float* W = (z == 0) ? Wq : ((z == 1) ? Wk : Wv);
  const float* Bias = (z == 0) ? Bq : ((z == 1) ? Bk : Bv);
  const float scale = (z == 0) ? 0.125f : 1.0f;   // bake 1/sqrt(64) into q
  unsigned short* out = qkv + (size_t)z * (size_t)(BB * NWIN * PN * EN);

  f32x4 acc[4][4];
#pragma unroll
  for (int i = 0; i < 4; ++i)
#pragma unroll
    for (int j = 0; j < 4; ++j) acc[i][j] = (f32x4){0.f, 0.f, 0.f, 0.f};

  for (int k0 = 0; k0 < EN; k0 += 64) {
    // ---- stage A tile (128x64 f32 -> bf16) ----
#pragma unroll
    for (int it = 0; it < 4; ++it) {
      int c = it * 256 + tid;             // 0..1023 chunks of 8 elems
      int r = c >> 3, cc = c & 7;
      const float* src = X + (size_t)(m0 + r) * EN + k0 + cc * 8;
      float4 f0 = *(const float4*)src;
      float4 f1 = *(const float4*)(src + 4);
      int off = (r * 128 + cc * 16) ^ ((r & 7) << 4);
      *(uint4*)((char*)As + off) =
          make_uint4(packbf2(f0.x, f0.y), packbf2(f0.z, f0.w),
                     packbf2(f1.x, f1.y), packbf2(f1.z, f1.w));
    }
    // ---- stage B tile (W rows n0..n0+127) ----
#pragma unroll
    for (int it = 0; it < 4; ++it) {
      int c = it * 256 + tid;
      int r = c >> 3, cc = c & 7;
      const float* src = W + (size_t)(n0 + r) * EN + k0 + cc * 8;
      float4 f0 = *(const float4*)src;
      float4 f1 = *(const float4*)(src + 4);
      int off = (r * 128 + cc * 16) ^ ((r & 7) << 4);
      *(uint4*)((char*)Bs + off) =
          make_uint4(packbf2(f0.x, f0.y), packbf2(f0.z, f0.w),
                     packbf2(f1.x, f1.y), packbf2(f1.z, f1.w));
    }
    __syncthreads();
    // ---- compute: 2 k-steps of 32 ----
#pragma unroll
    for (int ks = 0; ks < 2; ++ks) {
      bf16x8 af[4], bf_[4];
#pragma unroll
      for (int mt = 0; mt < 4; ++mt) {
        int row = wr + mt * 16 + lr;
        int off = (row * 128 + ks * 64 + (lg << 4)) ^ ((row & 7) << 4);
        af[mt] = *(const bf16x8*)((const char*)As + off);
      }
#pragma unroll
      for (int nt = 0; nt < 4; ++nt) {
        int row = wc + nt * 16 + lr;
        int off = (row * 128 + ks * 64 + (lg << 4)) ^ ((row & 7) << 4);
        bf_[nt] = *(const bf16x8*)((const char*)Bs + off);
      }
#pragma unroll
      for (int mt = 0; mt < 4; ++mt)
#pragma unroll
        for (int nt = 0; nt < 4; ++nt)
          acc[mt][nt] = __builtin_amdgcn_mfma_f32_16x16x32_bf16(
              af[mt], bf_[nt], acc[mt][nt], 0, 0, 0);
    }
    __syncthreads();
  }

  // ---- epilogue: +bias, *scale, scatter to [B][H][NW][P][D] bf16 ----
#pragma unroll
  for (int nt = 0; nt < 4; ++nt) {
    int f = n0 + wc + nt * 16 + lr;       // output feature
    float bias = Bias[f];
    int h = f >> 6, d = f & 63;
#pragma unroll
    for (int mt = 0; mt < 4; ++mt) {
#pragma unroll
      for (int reg = 0; reg < 4; ++reg) {
        int rowg = m0 + wr + mt * 16 + lg * 4 + reg;   // global patch row
        int b = rowg / (NWIN * PN);
        int rem = rowg - b * (NWIN * PN);
        int w = rem / PN;
        int p = rem - w * PN;
        size_t off = (((size_t)((b * HN + h) * NWIN + w) * PN + p) * DN + d);
        out[off] = f2bf((acc[mt][nt][reg] + bias) * scale);
      }
    }
  }
}

// ============ fused windowed attention, one block per (b,h,w) ==============
__global__ __launch_bounds__(256)
void attn_kernel(const unsigned short* __restrict__ qkv,
                 const float* __restrict__ pos_bias,
                 float* __restrict__ out) {
  __shared__ unsigned short Ks[PN * 64];       // K rows, swizzled 128B rows
  __shared__ unsigned short Vt[64 * 192];      // V^T: [d][p], swizzled 384B rows
  __shared__ unsigned short Pl[4][16 * 192];   // per-wave P strip, swizzled
  __shared__ float bias_tab[589];              // pos_bias [19][31]

  const int tid = threadIdx.x;
  const int lane = tid & 63;
  const int lr = lane & 15, lg = lane >> 4;
  const int wave = tid >> 6;

  const int bid = blockIdx.x;
  const int w = bid & 63;
  const int h = (bid >> 6) & 7;
  const int b = bid >> 9;

  const size_t TS = (size_t)BB * NWIN * PN * EN;     // elems per tensor
  const size_t bhw = (size_t)((b * HN + h) * NWIN + w);
  const unsigned short* q_base = qkv + bhw * (PN * DN);
  const unsigned short* k_base = q_base + TS;
  const unsigned short* v_base = q_base + 2 * TS;

  for (int i = tid; i < 589; i += 256) bias_tab[i] = pos_bias[i];

  // stage K (row-major, swizzled)
#pragma unroll
  for (int it = 0; it < 5; ++it) {
    int c = it * 256 + tid;              // 1280 chunks of 8 elems
    int r = c >> 3, cc = c & 7;
    uint4 kv = *(const uint4*)(k_base + r * 64 + cc * 8);
    int off = (r * 128 + cc * 16) ^ ((r & 7) << 4);
    *(uint4*)((char*)Ks + off) = kv;
  }
  // stage V transposed: Vt[d][p] = V[p][d]
#pragma unroll
  for (int it = 0; it < 5; ++it) {
    int c = it * 256 + tid;
    int dc = c / 160, p = c - dc * 160;
    union { uint4 v; unsigned short u[8]; } uu;
    uu.v = *(const uint4*)(v_base + p * 64 + dc * 8);
#pragma unroll
    for (int j = 0; j < 8; ++j) {
      int row = dc * 8 + j;
      int off = (row * 384 + p * 2) ^ ((row & 7) << 4);
      *(unsigned short*)((char*)Vt + off) = uu.u[j];
    }
  }
  __syncthreads();

  const int wy = w >> 3, wx = w & 7;
  const bool lastRow = (wy == 7), lastCol = (wx == 7);

  for (int mt = wave; mt < 10; mt += 4) {    // 16-row query strip per wave
    f32x4 s[10];
#pragma unroll
    for (int nt = 0; nt < 10; ++nt) s[nt] = (f32x4){0.f, 0.f, 0.f, 0.f};

    // S = Q K^T  (q already scaled by 1/8)
#pragma unroll
    for (int ks = 0; ks < 2; ++ks) {
      bf16x8 qa = *(const bf16x8*)(q_base + (mt * 16 + lr) * 64 + ks * 32 + lg * 8);
#pragma unroll
      for (int nt = 0; nt < 10; ++nt) {
        int krow = nt * 16 + lr;
        int off = (krow * 128 + ks * 64 + (lg << 4)) ^ ((krow & 7) << 4);
        bf16x8 kb = *(const bf16x8*)((const char*)Ks + off);
        s[nt] = __builtin_amdgcn_mfma_f32_16x16x32_bf16(qa, kb, s[nt], 0, 0, 0);
      }
    }

    // bias + shift-mask + wave-parallel softmax (rows spread over 16 lanes)
    float rinv[4];
#pragma unroll
    for (int reg = 0; reg < 4; ++reg) {
      int p = mt * 16 + lg * 4 + reg;        // query patch
      int vq = p >> 4, hq = p & 15;
#pragma unroll
      for (int nt = 0; nt < 10; ++nt) {
        int q = nt * 16 + lr;                // key patch
        int vk = q >> 4, hk = q & 15;
        bool msk = (lastRow && ((vq < 5) != (vk < 5))) ||
                   (lastCol && ((hq < 8) != (hk < 8)));
        int dv = vk - vq; dv += (dv < 0) ? 19 : 0;
        int dh = hk - hq; dh += (dh < 0) ? 31 : 0;
        float val = s[nt][reg] + bias_tab[dv * 31 + dh];
        s[nt][reg] = msk ? -1e30f : val;
      }
      float m = -1e30f;
#pragma unroll
      for (int nt = 0; nt < 10; ++nt) m = fmaxf(m, s[nt][reg]);
#pragma unroll
      for (int sh = 1; sh < 16; sh <<= 1) m = fmaxf(m, __shfl_xor(m, sh));
      float sum = 0.f;
#pragma unroll
      for (int nt = 0; nt < 10; ++nt) {
        float e = __expf(s[nt][reg] - m);
        s[nt][reg] = e;
        sum += e;
      }
#pragma unroll
      for (int sh = 1; sh < 16; sh <<= 1) sum += __shfl_xor(sum, sh);
      rinv[reg] = 1.f / sum;
    }

    // P (unnormalized) -> LDS to re-fragment as MFMA A-operand
#pragma unroll
    for (int reg = 0; reg < 4; ++reg) {
      int r = lg * 4 + reg;
#pragma unroll
      for (int nt = 0; nt < 10; ++nt) {
        int off = (r * 384 + (nt * 16 + lr) * 2) ^ ((r & 7) << 4);
        *(unsigned short*)((char*)Pl[wave] + off) = f2bf(s[nt][reg]);
      }
    }

    // O = P V
    f32x4 o[4];
#pragma unroll
    for (int dt = 0; dt < 4; ++dt) o[dt] = (f32x4){0.f, 0.f, 0.f, 0.f};
#pragma unroll
    for (int ks2 = 0; ks2 < 5; ++ks2) {
      int kofs = ks2 * 64 + lg * 16;         // bytes within row (k*2)
      int aoff = (lr * 384 + kofs) ^ ((lr & 7) << 4);
      bf16x8 pa = *(const bf16x8*)((const char*)Pl[wave] + aoff);
#pragma unroll
      for (int dt = 0; dt < 4; ++dt) {
        int vrow = dt * 16 + lr;
        int voff = (vrow * 384 + kofs) ^ ((vrow & 7) << 4);
        bf16x8 vb = *(const bf16x8*)((const char*)Vt + voff);
        o[dt] = __builtin_amdgcn_mfma_f32_16x16x32_bf16(pa, vb, o[dt], 0, 0, 0);
      }
    }

    // write out[b][w][p][h*64+d], normalize by 1/rowsum
    const size_t obase = ((size_t)(b * NWIN + w) * PN) * EN + h * DN;
#pragma unroll
    for (int dt = 0; dt < 4; ++dt) {
#pragma unroll
      for (int reg = 0; reg < 4; ++reg) {
        int p = mt * 16 + lg * 4 + reg;
        out[obase + (size_t)p * EN + dt * 16 + lr] = o[dt][reg] * rinv[reg];
      }
    }
  }
}

extern "C" void kernel_launch(void* const* d_in, const int* in_sizes, int n_in,
                              void* d_out, int out_size, void* d_ws, size_t ws_size,
                              hipStream_t stream) {
  const float* patches = (const float*)d_in[0];
  const float* wq = (const float*)d_in[1];
  const float* bq = (const float*)d_in[2];
  const float* wk = (const float*)d_in[3];
  const float* bk = (const float*)d_in[4];
  const float* wv = (const float*)d_in[5];
  const float* bv = (const float*)d_in[6];
  const float* pos_bias = (const float*)d_in[7];
  // d_in[8] = mask: recomputed analytically in-kernel, unused.

  unsigned short* qkv = (unsigned short*)d_ws;   // 3 x 41,943,040 bf16 = 252 MB
  float* out = (float*)d_out;

  proj_kernel<<<dim3(12, 640), dim3(256), 0, stream>>>(
      patches, wq, bq, wk, bk, wv, bv, qkv);
  attn_kernel<<<dim3(4096), dim3(256), 0, stream>>>(qkv, pos_bias, out);
}

// Round 3
// 811.283 us; speedup vs baseline: 1.0779x; 1.0779x over previous
//
#include <hip/hip_runtime.h>
#include <hip/hip_bf16.h>

typedef __attribute__((ext_vector_type(8))) short bf16x8;
typedef __attribute__((ext_vector_type(4))) float f32x4;

#define BB 8
#define NWIN 64
#define PN 160
#define EN 512
#define HN 8
#define DN 64

static __device__ __forceinline__ unsigned short f2bf(float f) {
  unsigned int u = __builtin_bit_cast(unsigned int, f);
  u += 0x7fffu + ((u >> 16) & 1u);
  return (unsigned short)(u >> 16);
}
static __device__ __forceinline__ unsigned int packbf2(float a, float b) {
  return (unsigned int)f2bf(a) | ((unsigned int)f2bf(b) << 16);
}

static __device__ __forceinline__ void gload16(const void* g, void* l) {
  __builtin_amdgcn_global_load_lds(
      (const __attribute__((address_space(1))) unsigned int*)g,
      (__attribute__((address_space(3))) unsigned int*)l, 16, 0, 0);
}

// ==== convert W (f32) -> Wb bf16, tiled [z][kt(8)][n(512)][8 chunks swz][8] ==
__global__ __launch_bounds__(256)
void convert_w(const float* __restrict__ Wq, const float* __restrict__ Wk,
               const float* __restrict__ Wv, unsigned short* __restrict__ Wb) {
  int t = blockIdx.x * 256 + threadIdx.x;        // 0..98303
  int z = t >> 15;
  int rem = t & 32767;
  int n = rem >> 6;
  int kc = rem & 63;                             // 8-elem chunk within row
  const float* W = (z == 0) ? Wq : ((z == 1) ? Wk : Wv);
  const float* src = W + n * EN + kc * 8;
  float4 f0 = *(const float4*)src;
  float4 f1 = *(const float4*)(src + 4);
  int kt = kc >> 3, kkc = kc & 7;
  unsigned short* dst =
      Wb + ((((size_t)z * 8 + kt) * 512 + n) * 8 + (kkc ^ (n & 7))) * 8;
  *(uint4*)dst = make_uint4(packbf2(f0.x, f0.y), packbf2(f0.z, f0.w),
                            packbf2(f1.x, f1.y), packbf2(f1.z, f1.w));
}

// ============ projection GEMM: qkv_z = (X @ W_z^T + b_z) (*0.125 for q) ====
// A: X f32 [81920 x 512], staged to LDS f32 via global_load_lds with
// XOR-pre-swizzled source columns. B: Wb bf16 (pre-swizzled), linear DMA.
__global__ __launch_bounds__(256)
void proj_gemm(const float* __restrict__ X, const unsigned short* __restrict__ Wb,
               const float* __restrict__ Bq, const float* __restrict__ Bk,
               const float* __restrict__ Bv, unsigned short* __restrict__ qkv) {
  __shared__ float As[128 * 64];            // 32 KB, 256 B rows, 16B-chunk XOR swz
  __shared__ unsigned short Bs[128 * 64];   // 16 KB, 128 B rows, swz baked in Wb

  const int tid = threadIdx.x;
  const int lane = tid & 63;
  const int lr = lane & 15, lg = lane >> 4;
  const int wave = tid >> 6;
  const int wr = (wave >> 1) * 64;
  const int wc = (wave & 1) * 64;

  // XCD-chunked mapping: 24 blocks (2 m-tiles x 12 nz) per chunk, same XCD.
  const int bid = blockIdx.x;               // 0..7679
  const int xcd = bid & 7;
  const int slot = bid >> 3;                // 0..959
  const int cic = slot / 24;                // chunk index within xcd (0..39)
  const int pic = slot - cic * 24;          // 0..23
  const int gchunk = cic * 8 + xcd;         // 0..319
  const int m0 = (gchunk * 2 + (pic >= 12 ? 1 : 0)) * 128;
  const int nz = (pic >= 12) ? pic - 12 : pic;
  const int z = nz >> 2;
  const int n0 = (nz & 3) * 128;

  const float* Bias = (z == 0) ? Bq : ((z == 1) ? Bk : Bv);
  const float scale = (z == 0) ? 0.125f : 1.0f;
  unsigned short* out = qkv + (size_t)z * (size_t)(BB * NWIN * PN * EN);

  f32x4 acc[4][4];
#pragma unroll
  for (int i = 0; i < 4; ++i)
#pragma unroll
    for (int j = 0; j < 4; ++j) acc[i][j] = (f32x4){0.f, 0.f, 0.f, 0.f};

  for (int kt = 0; kt < 8; ++kt) {
    const int k0 = kt * 64;
    // ---- DMA A tile: 8 wave-issues x 1 KB (4 rows each), swizzled source ----
    const float* xbase = X + (size_t)m0 * EN + k0;
#pragma unroll
    for (int i = 0; i < 8; ++i) {
      int rbase = (wave * 8 + i) * 4;
      int row = rbase + lg;
      const float* g = xbase + (size_t)row * EN + 4 * (lr ^ (row & 7));
      gload16(g, (char*)As + (wave * 8 + i) * 1024);
    }
    // ---- DMA B tile: 4 wave-issues x 1 KB, linear (swizzle baked) ----
    const unsigned short* wbase = Wb + (((size_t)z * 8 + kt) * 512 + n0) * 64;
#pragma unroll
    for (int i = 0; i < 4; ++i) {
      const unsigned short* g = wbase + (wave * 4 + i) * 512 + lane * 8;
      gload16(g, (char*)Bs + (wave * 4 + i) * 1024);
    }
    __syncthreads();

#pragma unroll
    for (int ks = 0; ks < 2; ++ks) {
      bf16x8 af[4], bf_[4];
#pragma unroll
      for (int mt = 0; mt < 4; ++mt) {
        int row = wr + mt * 16 + lr;
        int c0 = ks * 8 + lg * 2;
        f32x4 a0 = *(const f32x4*)((const char*)As +
                                   row * 256 + ((c0 ^ (row & 7)) << 4));
        f32x4 a1 = *(const f32x4*)((const char*)As +
                                   row * 256 + (((c0 + 1) ^ (row & 7)) << 4));
        union { bf16x8 v; __hip_bfloat162 h[4]; } ua;
        ua.h[0] = __float22bfloat162_rn(float2{a0.x, a0.y});
        ua.h[1] = __float22bfloat162_rn(float2{a0.z, a0.w});
        ua.h[2] = __float22bfloat162_rn(float2{a1.x, a1.y});
        ua.h[3] = __float22bfloat162_rn(float2{a1.z, a1.w});
        af[mt] = ua.v;
      }
#pragma unroll
      for (int nt = 0; nt < 4; ++nt) {
        int row = wc + nt * 16 + lr;
        int cb = ks * 4 + lg;
        bf_[nt] = *(const bf16x8*)((const char*)Bs +
                                   row * 128 + ((cb ^ (row & 7)) << 4));
      }
#pragma unroll
      for (int mt = 0; mt < 4; ++mt)
#pragma unroll
        for (int nt = 0; nt < 4; ++nt)
          acc[mt][nt] = __builtin_amdgcn_mfma_f32_16x16x32_bf16(
              af[mt], bf_[nt], acc[mt][nt], 0, 0, 0);
    }
    __syncthreads();
  }

  // ---- epilogue: +bias, *scale, scatter to [B][H][NW][P][D] bf16 ----
#pragma unroll
  for (int nt = 0; nt < 4; ++nt) {
    int f = n0 + wc + nt * 16 + lr;
    float bias = Bias[f];
    int h = f >> 6, d = f & 63;
#pragma unroll
    for (int mt = 0; mt < 4; ++mt) {
#pragma unroll
      for (int reg = 0; reg < 4; ++reg) {
        int rowg = m0 + wr + mt * 16 + lg * 4 + reg;
        int b = rowg / (NWIN * PN);
        int rem = rowg - b * (NWIN * PN);
        int w = rem / PN;
        int p = rem - w * PN;
        size_t off = (((size_t)((b * HN + h) * NWIN + w) * PN + p) * DN + d);
        out[off] = f2bf((acc[mt][nt][reg] + bias) * scale);
      }
    }
  }
}

// ============ fused windowed attention, one block per (b,h,w) ==============
// K read directly from global (20 KB tile, L2-resident); V^T + P in LDS.
__global__ __launch_bounds__(256)
void attn_kernel(const unsigned short* __restrict__ qkv,
                 const float* __restrict__ pos_bias,
                 float* __restrict__ out) {
  __shared__ unsigned short Vt[64 * 192];      // V^T: [d][p], swizzled 384B rows
  __shared__ unsigned short Pl[4][16 * 192];   // per-wave P strip, swizzled
  __shared__ float bias_tab[589];              // pos_bias [19][31]

  const int tid = threadIdx.x;
  const int lane = tid & 63;
  const int lr = lane & 15, lg = lane >> 4;
  const int wave = tid >> 6;

  const int bid = blockIdx.x;
  const int w = bid & 63;
  const int h = (bid >> 6) & 7;
  const int b = bid >> 9;

  const size_t TS = (size_t)BB * NWIN * PN * EN;
  const size_t bhw = (size_t)((b * HN + h) * NWIN + w);
  const unsigned short* q_base = qkv + bhw * (PN * DN);
  const unsigned short* k_base = q_base + TS;
  const unsigned short* v_base = q_base + 2 * TS;

  for (int i = tid; i < 589; i += 256) bias_tab[i] = pos_bias[i];

  // stage V transposed: Vt[d][p] = V[p][d]
#pragma unroll
  for (int it = 0; it < 5; ++it) {
    int c = it * 256 + tid;
    int dc = c / 160, p = c - dc * 160;
    union { uint4 v; unsigned short u[8]; } uu;
    uu.v = *(const uint4*)(v_base + p * 64 + dc * 8);
#pragma unroll
    for (int j = 0; j < 8; ++j) {
      int row = dc * 8 + j;
      int off = (row * 384 + p * 2) ^ ((row & 7) << 4);
      *(unsigned short*)((char*)Vt + off) = uu.u[j];
    }
  }
  __syncthreads();

  const int wy = w >> 3, wx = w & 7;
  const bool lastRow = (wy == 7), lastCol = (wx == 7);

  for (int mt = wave; mt < 10; mt += 4) {
    f32x4 s[10];
#pragma unroll
    for (int nt = 0; nt < 10; ++nt) s[nt] = (f32x4){0.f, 0.f, 0.f, 0.f};

    // S = Q K^T  (q pre-scaled by 1/8); K fragments straight from global/L2
#pragma unroll
    for (int ks = 0; ks < 2; ++ks) {
      bf16x8 qa = *(const bf16x8*)(q_base + (mt * 16 + lr) * 64 + ks * 32 + lg * 8);
#pragma unroll
      for (int nt = 0; nt < 10; ++nt) {
        bf16x8 kb = *(const bf16x8*)(k_base + (nt * 16 + lr) * 64 + ks * 32 + lg * 8);
        s[nt] = __builtin_amdgcn_mfma_f32_16x16x32_bf16(qa, kb, s[nt], 0, 0, 0);
      }
    }

    // bias + shift-mask + wave-parallel softmax
    float rinv[4];
#pragma unroll
    for (int reg = 0; reg < 4; ++reg) {
      int p = mt * 16 + lg * 4 + reg;
      int vq = p >> 4, hq = p & 15;
#pragma unroll
      for (int nt = 0; nt < 10; ++nt) {
        int q = nt * 16 + lr;
        int vk = q >> 4, hk = q & 15;
        bool msk = (lastRow && ((vq < 5) != (vk < 5))) ||
                   (lastCol && ((hq < 8) != (hk < 8)));
        int dv = vk - vq; dv += (dv < 0) ? 19 : 0;
        int dh = hk - hq; dh += (dh < 0) ? 31 : 0;
        float val = s[nt][reg] + bias_tab[dv * 31 + dh];
        s[nt][reg] = msk ? -1e30f : val;
      }
      float m = -1e30f;
#pragma unroll
      for (int nt = 0; nt < 10; ++nt) m = fmaxf(m, s[nt][reg]);
#pragma unroll
      for (int sh = 1; sh < 16; sh <<= 1) m = fmaxf(m, __shfl_xor(m, sh));
      float sum = 0.f;
#pragma unroll
      for (int nt = 0; nt < 10; ++nt) {
        float e = __expf(s[nt][reg] - m);
        s[nt][reg] = e;
        sum += e;
      }
#pragma unroll
      for (int sh = 1; sh < 16; sh <<= 1) sum += __shfl_xor(sum, sh);
      rinv[reg] = 1.f / sum;
    }

    // P -> LDS to re-fragment as MFMA A-operand
#pragma unroll
    for (int reg = 0; reg < 4; ++reg) {
      int r = lg * 4 + reg;
#pragma unroll
      for (int nt = 0; nt < 10; ++nt) {
        int off = (r * 384 + (nt * 16 + lr) * 2) ^ ((r & 7) << 4);
        *(unsigned short*)((char*)Pl[wave] + off) = f2bf(s[nt][reg]);
      }
    }

    // O = P V
    f32x4 o[4];
#pragma unroll
    for (int dt = 0; dt < 4; ++dt) o[dt] = (f32x4){0.f, 0.f, 0.f, 0.f};
#pragma unroll
    for (int ks2 = 0; ks2 < 5; ++ks2) {
      int kofs = ks2 * 64 + lg * 16;
      int aoff = (lr * 384 + kofs) ^ ((lr & 7) << 4);
      bf16x8 pa = *(const bf16x8*)((const char*)Pl[wave] + aoff);
#pragma unroll
      for (int dt = 0; dt < 4; ++dt) {
        int vrow = dt * 16 + lr;
        int voff = (vrow * 384 + kofs) ^ ((vrow & 7) << 4);
        bf16x8 vb = *(const bf16x8*)((const char*)Vt + voff);
        o[dt] = __builtin_amdgcn_mfma_f32_16x16x32_bf16(pa, vb, o[dt], 0, 0, 0);
      }
    }

    const size_t obase = ((size_t)(b * NWIN + w) * PN) * EN + h * DN;
#pragma unroll
    for (int dt = 0; dt < 4; ++dt) {
#pragma unroll
      for (int reg = 0; reg < 4; ++reg) {
        int p = mt * 16 + lg * 4 + reg;
        out[obase + (size_t)p * EN + dt * 16 + lr] = o[dt][reg] * rinv[reg];
      }
    }
  }
}

extern "C" void kernel_launch(void* const* d_in, const int* in_sizes, int n_in,
                              void* d_out, int out_size, void* d_ws, size_t ws_size,
                              hipStream_t stream) {
  const float* patches = (const float*)d_in[0];
  const float* wq = (const float*)d_in[1];
  const float* bq = (const float*)d_in[2];
  const float* wk = (const float*)d_in[3];
  const float* bk = (const float*)d_in[4];
  const float* wv = (const float*)d_in[5];
  const float* bv = (const float*)d_in[6];
  const float* pos_bias = (const float*)d_in[7];
  // d_in[8] = mask: recomputed analytically in-kernel, unused.

  unsigned short* qkv = (unsigned short*)d_ws;          // 3 x 41,943,040 bf16
  unsigned short* Wb = qkv + (size_t)3 * BB * NWIN * PN * EN;  // +1.5 MB
  float* out = (float*)d_out;

  convert_w<<<dim3(384), dim3(256), 0, stream>>>(wq, wk, wv, Wb);
  proj_gemm<<<dim3(7680), dim3(256), 0, stream>>>(patches, Wb, bq, bk, bv, qkv);
  attn_kernel<<<dim3(4096), dim3(256), 0, stream>>>(qkv, pos_bias, out);
}